// Round 4
// baseline (782.837 us; speedup 1.0000x reference)
//
#include <hip/hip_runtime.h>
#include <hip/hip_bf16.h>

typedef __attribute__((ext_vector_type(8))) short  s8v;   // 8 x bf16 bits
typedef __attribute__((ext_vector_type(4))) float  f4v;

#define XH 256
#define XW 256
#define PLANE 65536
#define X16W 258
#define X16PITCH (X16W * 128)            // bytes per padded NHWC row (33024)
#define X16IMG ((size_t)X16PITCH * 258)  // bytes per image (8,520,192)

__device__ __forceinline__ unsigned short f2bf(float f){
  __hip_bfloat16 h = __float2bfloat16(f);          // HW RNE cvt
  return __builtin_bit_cast(unsigned short, h);
}
__device__ __forceinline__ float bf2f(unsigned short h){
  unsigned int u = ((unsigned int)h) << 16;
  return __builtin_bit_cast(float, u);
}

// ---------------- K1: NCHW f32 -> padded NHWC bf16 transpose + fused pool ----
// Block = (b, slab of 4 rows). LDS tile [256 w][16 slots x 8B], slot swizzled
// slot = cgrp ^ ((w>>2)&15) so both write (w=4*lane+e) and read (16 lanes same
// w-group, all q) sit at the 512B/instr bank floor.
__global__ __launch_bounds__(256) void tr_k(const float* __restrict__ x,
    char* __restrict__ x16, float* __restrict__ part){
  __shared__ __align__(16) char tile[256 * 128];
  __shared__ float red[16][16][4];
  const int bid = blockIdx.x, t = threadIdx.x;
  const int b = bid >> 6, slab = bid & 63;
  char* xb = x16 + (size_t)b * X16IMG;
  const float* xsrc = x + (size_t)b * 64 * PLANE;
  const int lane = t & 63, q = t & 15, wg16 = t >> 4;   // wg16: 0..15 (block-wide)
  float psum[4] = {0.f, 0.f, 0.f, 0.f};

  // border zeroing (disjoint from interior stores; no ordering needed)
  if(t < 128){                       // col borders (wg=-1,256) for own 4 rows
    int side = t >> 6, r = (t >> 4) & 3, qq = t & 15;
    char* p = xb + (size_t)(slab * 4 + r + 1) * X16PITCH
                 + (side ? (size_t)257 * 128 : 0) + qq * 8;
    *(unsigned long long*)p = 0ULL;
  }
  if(slab == 0 || slab == 63){       // full top/bottom padded rows
    char* rp = xb + (slab ? (size_t)257 * X16PITCH : 0);
    for(int px = wg16; px < 258; px += 16)
      *(unsigned long long*)(rp + (size_t)px * 128 + q * 8) = 0ULL;
  }

  for(int r = 0; r < 4; ++r){
    const int hg = slab * 4 + r;
    // ---- load f4v (4w) x 4 planes, in-register transpose, LDS write
    #pragma unroll
    for(int it = 0; it < 4; ++it){
      const int cgrp = (t >> 6) + 4 * it;              // 0..15, wave-uniform
      const float* bp = xsrc + (size_t)(cgrp << 2) * PLANE + hg * 256 + (lane << 2);
      f4v v0 = *(const f4v*)bp;
      f4v v1 = *(const f4v*)(bp + PLANE);
      f4v v2 = *(const f4v*)(bp + 2 * PLANE);
      f4v v3 = *(const f4v*)(bp + 3 * PLANE);
      const int slot = cgrp ^ (lane & 15);
      #pragma unroll
      for(int e = 0; e < 4; ++e){
        int w = (lane << 2) + e;
        unsigned long long d =
            (unsigned long long)f2bf(v0[e])
          | ((unsigned long long)f2bf(v1[e]) << 16)
          | ((unsigned long long)f2bf(v2[e]) << 32)
          | ((unsigned long long)f2bf(v3[e]) << 48);
        *(unsigned long long*)(tile + w * 128 + (slot << 3)) = d;
      }
    }
    __syncthreads();
    // ---- store NHWC (coalesced 8B/lane) + pool accumulate
    char* rowp = xb + (size_t)(hg + 1) * X16PITCH + 128;   // wg+1 offset
    #pragma unroll 4
    for(int i = 0; i < 16; ++i){
      int w = i * 16 + wg16;
      unsigned long long v = *(const unsigned long long*)
          (tile + w * 128 + (((q ^ ((w >> 2) & 15))) << 3));
      unsigned short* sp = (unsigned short*)&v;
      psum[0] += bf2f(sp[0]); psum[1] += bf2f(sp[1]);
      psum[2] += bf2f(sp[2]); psum[3] += bf2f(sp[3]);
      *(unsigned long long*)(rowp + (size_t)w * 128 + (q << 3)) = v;
    }
    __syncthreads();
  }
  // ---- block pool reduction: thread (wg16, q) -> red, then 64 threads sum
  red[wg16][q][0] = psum[0]; red[wg16][q][1] = psum[1];
  red[wg16][q][2] = psum[2]; red[wg16][q][3] = psum[3];
  __syncthreads();
  if(t < 64){
    int qq = t >> 2, j = t & 3;
    float s = 0.f;
    #pragma unroll
    for(int k = 0; k < 16; ++k) s += red[k][qq][j];
    part[bid * 64 + (qq << 2) + j] = s;        // raw sum over 4 rows x 256 w
  }
}

// ---------------- K2: pool reduce + direction MLP + BN-folded weight pack ----
// PK layout (bf16): byte = s*4096 + n*64 + g*16 + j*2 (s=K32-step, n=oc,
// g=lane>>4, j=0..7). k = 32s + 8g + j = tap*64 + c, tap = s>>1,
// c = 32*(s&1) + 8g + j.
__global__ __launch_bounds__(256) void prep_k(const float* __restrict__ convw,
    const float* __restrict__ convb, const float* __restrict__ gamma,
    const float* __restrict__ beta,  const float* __restrict__ mean,
    const float* __restrict__ var,   const float* __restrict__ d1w,
    const float* __restrict__ d1b,   const float* __restrict__ d2w,
    const float* __restrict__ d2b,   const float* __restrict__ part,
    float* __restrict__ dirv, float* __restrict__ bias2,
    unsigned short* __restrict__ pk, float* __restrict__ outdir){
  int blk = blockIdx.x, t = threadIdx.x;
  if(blk == 0){
    __shared__ float pooled_s[16][64];
    __shared__ float h1s[16][8];
    for(int p = t; p < 1024; p += 256){        // (b,c) sums over 64 slabs
      int b = p >> 6, c = p & 63;
      float s = 0.f;
      for(int sl = 0; sl < 64; ++sl) s += part[((b << 6) | sl) * 64 + c];
      pooled_s[b][c] = s * (1.f / 65536.f);
    }
    __syncthreads();
    if(t < 128){                               // h1[b][o] over 128 lanes
      int b = t >> 3, o = t & 7;
      float a = d1b[o];
      #pragma unroll 8
      for(int c = 0; c < 64; ++c) a = fmaf(pooled_s[b][c], d1w[o * 64 + c], a);
      h1s[b][o] = fmaxf(a, 0.f);
    } else if(t >= 128 && t < 192){
      int oc = t - 128;
      float sc = gamma[oc] * rsqrtf(var[oc] + 1e-5f);
      bias2[oc] = (convb[oc] - mean[oc]) * sc + beta[oc];
    }
    __syncthreads();
    if(t < 16){
      float logit = d2b[0];
      #pragma unroll
      for(int o = 0; o < 8; ++o) logit = fmaf(h1s[t][o], d2w[o], logit);
      float dv = 1.f / (1.f + __expf(-logit));
      dirv[t] = dv;
      outdir[t] = dv;                          // direction output (tuple tail)
    }
  } else {
    int idx = ((blk - 1) << 8) + t;            // < 36864
    int j = idx & 7, g = (idx >> 3) & 3, n = (idx >> 5) & 63, s = idx >> 11;
    int c = ((s & 1) << 5) + (g << 3) + j, tap = s >> 1;
    float sc = gamma[n] * rsqrtf(var[n] + 1e-5f);
    pk[idx] = f2bf(convw[(n * 64 + c) * 9 + tap] * sc);
  }
}

// ---------------- K3: fused conv+BN+relu+attn+sigmoid+mul (no x-LDS) --------
// Block = 256 thr (4 waves), tile 4 rows x 64 cols. A-fragments read directly
// from padded NHWC bf16 x16 (no guards needed). 1KB LDS -> 4 blocks/CU.
__global__ __launch_bounds__(256, 4) void main_k(const char* __restrict__ x16,
    const float* __restrict__ attnw, const float* __restrict__ attnb,
    const float* __restrict__ dirv,  const float* __restrict__ bias2,
    const unsigned short* __restrict__ pk, float* __restrict__ out){
  __shared__ float att_s[256];

  const int bid = blockIdx.x;
  const int bs  = ((bid & 7) << 9) | (bid >> 3);     // XCD swizzle (4096%8==0)
  const int wblk = bs & 3, hblk = (bs >> 2) & 63, b = bs >> 8;
  const int w0 = wblk << 6, h0 = hblk << 2;
  const int t = threadIdx.x, lane = t & 63, wv = t >> 6;
  const int lm = lane & 15, lg = lane >> 4;
  const char* xb = x16 + (size_t)b * X16IMG;

  const char* pkl = (const char*)pk + lm * 64 + (lg << 4);

#define BLOAD(BUF, S) { \
    _Pragma("unroll") \
    for(int jn = 0; jn < 4; ++jn) BUF[jn] = *(const s8v*)(pkl + ((S) << 12) + (jn << 10)); }

  s8v bb0[4], bb1[4];
  BLOAD(bb0, 0); BLOAD(bb1, 1);

  // A row bases: padded row (h0+wv+dh), dh=0..2 ; col base (w0+lm) padded
  const char* rb0 = xb + (size_t)(h0 + wv)     * X16PITCH + (size_t)(w0 + lm) * 128 + (lg << 4);
  const char* rb1 = xb + (size_t)(h0 + wv + 1) * X16PITCH + (size_t)(w0 + lm) * 128 + (lg << 4);
  const char* rb2 = xb + (size_t)(h0 + wv + 2) * X16PITCH + (size_t)(w0 + lm) * 128 + (lg << 4);

  f4v acc[4][4];
  #pragma unroll
  for(int i = 0; i < 4; ++i)
    #pragma unroll
    for(int j = 0; j < 4; ++j) acc[i][j] = (f4v){0.f, 0.f, 0.f, 0.f};

#define MF(AFR, BUF) { \
    _Pragma("unroll") \
    for(int i = 0; i < 4; ++i){ _Pragma("unroll") for(int j = 0; j < 4; ++j) \
      acc[i][j] = __builtin_amdgcn_mfma_f32_16x16x32_bf16(AFR[i], BUF[j], acc[i][j], 0, 0, 0); } }
// step S: tap p=S>>1 -> dh=p/3 (row base), dw=p%3 ; odd S = channels 32..63
#define STEPX(S, BUF) { \
    s8v afr[4]; \
    const char* rp = ((S) >> 1) / 3 == 0 ? rb0 : (((S) >> 1) / 3 == 1 ? rb1 : rb2); \
    const int off = (((S) >> 1) % 3) * 128 + (((S) & 1) << 6); \
    _Pragma("unroll") \
    for(int i = 0; i < 4; ++i) afr[i] = *(const s8v*)(rp + off + (i << 11)); \
    __builtin_amdgcn_s_setprio(1); \
    MF(afr, BUF); \
    __builtin_amdgcn_s_setprio(0); \
    if((S) + 2 < 18) BLOAD(BUF, (S) + 2); }

  STEPX(0,  bb0) STEPX(1,  bb1) STEPX(2,  bb0) STEPX(3,  bb1)
  STEPX(4,  bb0) STEPX(5,  bb1) STEPX(6,  bb0) STEPX(7,  bb1)
  STEPX(8,  bb0) STEPX(9,  bb1) STEPX(10, bb0) STEPX(11, bb1)
  STEPX(12, bb0) STEPX(13, bb1) STEPX(14, bb0) STEPX(15, bb1)
  STEPX(16, bb0) STEPX(17, bb1)

  // ---- epilogue: att = sum_oc attn_w[oc] * relu(z + bias2[oc])
  float aw[4], bz[4];
  #pragma unroll
  for(int j = 0; j < 4; ++j){ aw[j] = attnw[(j << 4) + lm]; bz[j] = bias2[(j << 4) + lm]; }
  #pragma unroll
  for(int i = 0; i < 4; ++i){
    #pragma unroll
    for(int r = 0; r < 4; ++r){
      float lsum = 0.f;
      #pragma unroll
      for(int j = 0; j < 4; ++j)
        lsum = fmaf(aw[j], fmaxf(acc[i][j][r] + bz[j], 0.f), lsum);
      lsum += __shfl_xor(lsum, 8);
      lsum += __shfl_xor(lsum, 4);
      lsum += __shfl_xor(lsum, 2);
      lsum += __shfl_xor(lsum, 1);
      if(lm == (i << 2) + r) att_s[(wv << 6) + (i << 4) + (lg << 2) + r] = lsum;
    }
  }
  __syncthreads();

  // ---- output: out = x * sigmoid((att + attn_b) * mask), x re-read from x16
  const int col = lane, row = wv;
  const float dir = dirv[b];
  const int h = h0 + row;
  const float jf = (float)h * (1.f / 256.f);
  const float maskv = (dir > 0.5f) ? (0.5f + 0.5f * jf) : (1.f - 0.5f * jf);
  const float att = att_s[(row << 6) + col] + attnb[0];
  const float sg = 1.f / (1.f + __expf(-att * maskv));
  const char* xr = xb + (size_t)(h + 1) * X16PITCH + (size_t)(w0 + col + 1) * 128;
  float* op = out + (size_t)b * 64 * PLANE + (size_t)h * XW + w0 + col;
  #pragma unroll
  for(int k = 0; k < 8; ++k){
    s8v v = *(const s8v*)(xr + (k << 4));
    #pragma unroll
    for(int e = 0; e < 8; ++e){
      op[(size_t)((k << 3) + e) * PLANE] = bf2f((unsigned short)v[e]) * sg;
    }
  }
#undef BLOAD
#undef MF
#undef STEPX
}

extern "C" void kernel_launch(void* const* d_in, const int* in_sizes, int n_in,
                              void* d_out, int out_size, void* d_ws, size_t ws_size,
                              hipStream_t stream){
  const float* x     = (const float*)d_in[0];
  const float* convw = (const float*)d_in[1];
  const float* convb = (const float*)d_in[2];
  const float* gamma = (const float*)d_in[3];
  const float* beta  = (const float*)d_in[4];
  const float* mean  = (const float*)d_in[5];
  const float* var   = (const float*)d_in[6];
  const float* attnw = (const float*)d_in[7];
  const float* attnb = (const float*)d_in[8];
  const float* d1w   = (const float*)d_in[9];
  const float* d1b   = (const float*)d_in[10];
  const float* d2w   = (const float*)d_in[11];
  const float* d2b   = (const float*)d_in[12];
  float* out = (float*)d_out;
  char*  ws  = (char*)d_ws;
  // ws layout: dirv @0 (64B) | bias2 @256 (256B) | pk @1024 (73728B)
  //            part @74752 (262144B) | x16 @336896 (136,323,072B, 128-aligned)
  float* dirv   = (float*)ws;
  float* bias2  = (float*)(ws + 256);
  unsigned short* pk = (unsigned short*)(ws + 1024);
  float* part   = (float*)(ws + 74752);
  char*  x16    = ws + 336896;
  float* outdir = out + (size_t)16 * 64 * 256 * 256;

  tr_k<<<1024, 256, 0, stream>>>(x, x16, part);
  prep_k<<<145, 256, 0, stream>>>(convw, convb, gamma, beta, mean, var,
                                  d1w, d1b, d2w, d2b, part, dirv, bias2, pk, outdir);
  main_k<<<4096, 256, 0, stream>>>(x16, attnw, attnb, dirv, bias2, pk, out);
}

// Round 6
// 601.349 us; speedup vs baseline: 1.3018x; 1.3018x over previous
//
#include <hip/hip_runtime.h>
#include <hip/hip_bf16.h>

typedef __attribute__((ext_vector_type(8))) short  s8v;   // 8 x bf16 bits
typedef __attribute__((ext_vector_type(4))) float  f4v;
typedef __attribute__((ext_vector_type(4))) unsigned short u4v;

#define XH 256
#define XW 256
#define PLANE 65536
#define PCW 66          // padded tile width (64 + 2 halo)

__device__ __forceinline__ unsigned short f2bf(float f){
  __hip_bfloat16 h = __float2bfloat16(f);          // HW RNE cvt
  return __builtin_bit_cast(unsigned short, h);
}
__device__ __forceinline__ float bf2f(unsigned short h){
  unsigned int u = ((unsigned int)h) << 16;
  return __builtin_bit_cast(float, u);
}

// ---------------- K1: per-(b,c) plane mean ----------------
__global__ __launch_bounds__(256) void pool_k(const float* __restrict__ x,
                                              float* __restrict__ pooled){
  int plane = blockIdx.x, t = threadIdx.x;
  const f4v* p = (const f4v*)(x + (size_t)plane * PLANE);
  float s = 0.f;
  #pragma unroll 8
  for(int it = 0; it < 64; ++it){
    f4v v = p[t + (it << 8)];
    s += v[0] + v[1] + v[2] + v[3];
  }
  #pragma unroll
  for(int m = 32; m >= 1; m >>= 1) s += __shfl_xor(s, m);
  __shared__ float ps[4];
  if((t & 63) == 0) ps[t >> 6] = s;
  __syncthreads();
  if(t == 0) pooled[plane] = (ps[0] + ps[1] + ps[2] + ps[3]) * (1.f / 65536.f);
}

// ---------------- K2: direction MLP + BN-folded weight pack ----------------
// PK layout (bf16): byte = s*4096 + n*64 + g*16 + j*2 (s=K32-step, n=oc,
// g=lane>>4, j=0..7). k = 32s + 8g + j = tap*64 + c, tap = s>>1,
// c = 32*(s&1) + 8g + j.
__global__ __launch_bounds__(256) void prep_k(const float* __restrict__ convw,
    const float* __restrict__ convb, const float* __restrict__ gamma,
    const float* __restrict__ beta,  const float* __restrict__ mean,
    const float* __restrict__ var,   const float* __restrict__ d1w,
    const float* __restrict__ d1b,   const float* __restrict__ d2w,
    const float* __restrict__ d2b,   const float* __restrict__ pooled,
    float* __restrict__ dirv, float* __restrict__ bias2,
    unsigned short* __restrict__ pk, float* __restrict__ outdir){
  int blk = blockIdx.x, t = threadIdx.x;
  if(blk == 0){
    __shared__ float h1s[16][8];
    if(t < 128){                       // h1[b][o] over 128 lanes
      int b = t >> 3, o = t & 7;
      float a = d1b[o];
      #pragma unroll 8
      for(int c = 0; c < 64; ++c) a = fmaf(pooled[b * 64 + c], d1w[o * 64 + c], a);
      h1s[b][o] = fmaxf(a, 0.f);
    } else if(t >= 128 && t < 192){
      int oc = t - 128;
      float sc = gamma[oc] * rsqrtf(var[oc] + 1e-5f);
      bias2[oc] = (convb[oc] - mean[oc]) * sc + beta[oc];
    }
    __syncthreads();
    if(t < 16){
      float logit = d2b[0];
      #pragma unroll
      for(int o = 0; o < 8; ++o) logit = fmaf(h1s[t][o], d2w[o], logit);
      float dv = 1.f / (1.f + __expf(-logit));
      dirv[t] = dv;
      outdir[t] = dv;                  // direction output (tuple tail)
    }
  } else {
    int idx = ((blk - 1) << 8) + t;    // < 36864
    int j = idx & 7, g = (idx >> 3) & 3, n = (idx >> 5) & 63, s = idx >> 11;
    int c = ((s & 1) << 5) + (g << 3) + j, tap = s >> 1;
    float sc = gamma[n] * rsqrtf(var[n] + 1e-5f);
    pk[idx] = f2bf(convw[(n * 64 + c) * 9 + tap] * sc);
  }
}

// ---------------- K3: fused conv+BN+relu+attn+sigmoid+mul ----------------
// Block = 256 thr (4 waves). Tile = 4 rows x 64 cols. LDS xs: [pix][64 ch]
// bf16, 16B-slot swizzle: slot16 = (cgrp>>1) ^ ((pix>>2)&7). Staging keeps
// chunk lane-minor (coalesced global) AND pix>>2 consecutive across lanes ->
// writes sweep all 8 slots (2-way, free). Reads are 16B-aligned, channel
// order preserved.
__global__ __launch_bounds__(256, 3) void main_k(const float* __restrict__ x,
    const float* __restrict__ attnw, const float* __restrict__ attnb,
    const float* __restrict__ dirv,  const float* __restrict__ bias2,
    const unsigned short* __restrict__ pk, float* __restrict__ out){
  __shared__ __align__(16) char lds[6 * PCW * 128 + 4 * 64 * 4];
  float* att_s = (float*)(lds + 6 * PCW * 128);

  const int bid = blockIdx.x;
  const int bs  = ((bid & 7) << 9) | (bid >> 3);     // XCD swizzle (4096%8==0)
  const int wblk = bs & 3, hblk = (bs >> 2) & 63, b = bs >> 8;
  const int w0 = wblk << 6, h0 = hblk << 2;
  const int t = threadIdx.x, lane = t & 63, wv = t >> 6;
  const int lm = lane & 15, lg = lane >> 4;
  const size_t bbase = (size_t)b * 64 * PLANE;

  const char* pkl = (const char*)pk + lm * 64 + (lg << 4);

#define BLOAD(BUF, S) { \
    _Pragma("unroll") \
    for(int jn = 0; jn < 4; ++jn) BUF[jn] = *(const s8v*)(pkl + ((S) << 12) + (jn << 10)); }

  // first 3 K-steps' weight loads fly under the HBM staging
  s8v bb0[4], bb1[4], bb2[4];
  BLOAD(bb0, 0); BLOAD(bb1, 1); BLOAD(bb2, 2);

  // ---- stage x halo (6 rows x 66 cols x 64 ch) as bf16 -> [pix][c] swizzled
  #pragma unroll 2
  for(int it = 0; it < 7; ++it){
    int task = t + (it << 8);
    if(task < 1728){                       // chunk(18) minor | hh(6) | cgrp(16)
      int chunk = task % 18;
      int rem   = task / 18;
      int hh = rem % 6, cgrp = rem / 6;
      int hhg = h0 - 1 + hh;
      int wcg = w0 - 4 + (chunk << 2);     // 16B-aligned float4 start
      f4v v0 = {0,0,0,0}, v1 = {0,0,0,0}, v2 = {0,0,0,0}, v3 = {0,0,0,0};
      if(hhg >= 0 && hhg < XH && wcg >= 0 && wcg + 3 < XW){
        const float* bp = x + bbase + (size_t)(cgrp << 2) * PLANE + (size_t)hhg * XW + wcg;
        v0 = *(const f4v*)bp;
        v1 = *(const f4v*)(bp + PLANE);
        v2 = *(const f4v*)(bp + 2 * PLANE);
        v3 = *(const f4v*)(bp + 3 * PLANE);
      }
      #pragma unroll
      for(int e = 0; e < 4; ++e){
        int pc = (chunk << 2) - 3 + e;
        if(pc >= 0 && pc < PCW){
          int pix = hh * PCW + pc;
          int s16 = (cgrp >> 1) ^ ((pix >> 2) & 7);
          int bo  = pix * 128 + (s16 << 4) + ((cgrp & 1) << 3);
          unsigned long long d =
              (unsigned long long)f2bf(v0[e])
            | ((unsigned long long)f2bf(v1[e]) << 16)
            | ((unsigned long long)f2bf(v2[e]) << 32)
            | ((unsigned long long)f2bf(v3[e]) << 48);
          *(unsigned long long*)(lds + bo) = d;
        }
      }
    }
  }
  __syncthreads();

  // ---- implicit-GEMM K loop: 18 steps of K=32, no barriers, ring-3 prefetch
  f4v acc[4][4];
  #pragma unroll
  for(int i = 0; i < 4; ++i)
    #pragma unroll
    for(int j = 0; j < 4; ++j) acc[i][j] = (f4v){0.f, 0.f, 0.f, 0.f};

  const int pixb = (wv + 1) * PCW + lm + 1;

#define ALOAD(AFR, D, SCH) { \
    _Pragma("unroll") \
    for(int i = 0; i < 4; ++i){ int pix = pixb + (i << 4) + (D); \
      int sl = ((SCH) ^ ((pix >> 2) & 7)) << 4; \
      AFR[i] = *(const s8v*)(lds + pix * 128 + sl); } }
#define MF(AFR, BUF) { \
    _Pragma("unroll") \
    for(int i = 0; i < 4; ++i){ _Pragma("unroll") for(int j = 0; j < 4; ++j) \
      acc[i][j] = __builtin_amdgcn_mfma_f32_16x16x32_bf16(AFR[i], BUF[j], acc[i][j], 0, 0, 0); } }
#define STEPX(S, BUF) { \
    s8v afr[4]; \
    const int dd = (((S) >> 1) / 3 - 1) * PCW + (((S) >> 1) % 3 - 1); \
    ALOAD(afr, dd, lg + (((S) & 1) << 2)); \
    __builtin_amdgcn_s_setprio(1); \
    MF(afr, BUF); \
    __builtin_amdgcn_s_setprio(0); \
    if((S) + 3 < 18) BLOAD(BUF, (S) + 3); }

  STEPX(0,  bb0) STEPX(1,  bb1) STEPX(2,  bb2)
  STEPX(3,  bb0) STEPX(4,  bb1) STEPX(5,  bb2)
  STEPX(6,  bb0) STEPX(7,  bb1) STEPX(8,  bb2)
  STEPX(9,  bb0) STEPX(10, bb1) STEPX(11, bb2)
  STEPX(12, bb0) STEPX(13, bb1) STEPX(14, bb2)
  STEPX(15, bb0) STEPX(16, bb1) STEPX(17, bb2)

  // ---- epilogue: att = sum_oc attn_w[oc] * relu(z + bias2[oc])
  float aw[4], bz[4];
  #pragma unroll
  for(int j = 0; j < 4; ++j){ aw[j] = attnw[(j << 4) + lm]; bz[j] = bias2[(j << 4) + lm]; }
  #pragma unroll
  for(int i = 0; i < 4; ++i){
    #pragma unroll
    for(int r = 0; r < 4; ++r){
      float lsum = 0.f;
      #pragma unroll
      for(int j = 0; j < 4; ++j)
        lsum = fmaf(aw[j], fmaxf(acc[i][j][r] + bz[j], 0.f), lsum);
      lsum += __shfl_xor(lsum, 8);
      lsum += __shfl_xor(lsum, 4);
      lsum += __shfl_xor(lsum, 2);
      lsum += __shfl_xor(lsum, 1);
      if(lm == (i << 2) + r) att_s[(wv << 6) + (i << 4) + (lg << 2) + r] = lsum;
    }
  }
  __syncthreads();

  // ---- output: out = x * sigmoid((att + attn_b) * mask)
  const int col = lane, row = wv;
  const float dir = dirv[b];
  const int h = h0 + row;
  const float jf = (float)h * (1.f / 256.f);
  const float maskv = (dir > 0.5f) ? (0.5f + 0.5f * jf) : (1.f - 0.5f * jf);
  const float att = att_s[(row << 6) + col] + attnb[0];
  const float sg = 1.f / (1.f + __expf(-att * maskv));
  const int pix = (row + 1) * PCW + (col + 1);
  const char* xr = lds + pix * 128;
  const int pq = (pix >> 2) & 7;
  float* op = out + bbase + (size_t)h * XW + w0 + col;
  #pragma unroll
  for(int k = 0; k < 8; ++k){
    s8v v = *(const s8v*)(xr + ((k ^ pq) << 4));
    #pragma unroll
    for(int e = 0; e < 8; ++e){
      op[(size_t)((k << 3) + e) * PLANE] = bf2f((unsigned short)v[e]) * sg;
    }
  }
#undef ALOAD
#undef BLOAD
#undef MF
#undef STEPX
}

extern "C" void kernel_launch(void* const* d_in, const int* in_sizes, int n_in,
                              void* d_out, int out_size, void* d_ws, size_t ws_size,
                              hipStream_t stream){
  const float* x     = (const float*)d_in[0];
  const float* convw = (const float*)d_in[1];
  const float* convb = (const float*)d_in[2];
  const float* gamma = (const float*)d_in[3];
  const float* beta  = (const float*)d_in[4];
  const float* mean  = (const float*)d_in[5];
  const float* var   = (const float*)d_in[6];
  const float* attnw = (const float*)d_in[7];
  const float* attnb = (const float*)d_in[8];
  const float* d1w   = (const float*)d_in[9];
  const float* d1b   = (const float*)d_in[10];
  const float* d2w   = (const float*)d_in[11];
  const float* d2b   = (const float*)d_in[12];
  float* out = (float*)d_out;
  char*  ws  = (char*)d_ws;
  // ws: pooled @0 (4KB) | dirv @4096 | bias2 @4352 | pk @5120 (73728B)
  float* pooled = (float*)ws;
  float* dirv   = (float*)(ws + 4096);
  float* bias2  = (float*)(ws + 4352);
  unsigned short* pk = (unsigned short*)(ws + 5120);
  float* outdir = out + (size_t)16 * 64 * 256 * 256;

  pool_k<<<1024, 256, 0, stream>>>(x, pooled);
  prep_k<<<145, 256, 0, stream>>>(convw, convb, gamma, beta, mean, var,
                                  d1w, d1b, d2w, d2b, pooled, dirv, bias2, pk, outdir);
  main_k<<<4096, 256, 0, stream>>>(x, attnw, attnb, dirv, bias2, pk, out);
}